// Round 8
// baseline (273.537 us; speedup 1.0000x reference)
//
#include <hip/hip_runtime.h>
#include <cmath>

#define B_ 32
#define N_ 4096
#define IN_DIM 125
#define ADIM 128
#define KDIM 64
#define DMODEL 1024
#define HID 64
#define KEFF 256
#define EPS_ 1e-6f

// ---------- k0: convert MLP weights to f64 (once per launch) ----------
// Kept separate: r5 proved inlining the f32->f64 cvt into k1's loop costs
// +16us of f64-pipe time vs ~12us for this launch+run.
__global__ __launch_bounds__(256) void k0_cvt(
    const float* __restrict__ W1, const float* __restrict__ b1,
    const float* __restrict__ W2, const float* __restrict__ b2,
    double* __restrict__ W1D, double* __restrict__ b1D,
    double* __restrict__ W2D, double* __restrict__ b2D)
{
  int t = blockIdx.x * 256 + threadIdx.x;
  if (t < IN_DIM * HID) W1D[t] = (double)W1[t];
  if (t < HID) { b1D[t] = (double)b1[t]; W2D[t] = (double)W2[t]; }
  if (t == 0) b2D[0] = (double)b2[0];
}

// ---------- k1: saliency MLP in fp64 (r0 version — all-time best) ----------
// r0-r7 verdict: 64 pts/block, s_load f64-W, 1 pt/lane = 58-64us at
// VALU ~52-58%, occ ~70%. Every restructure regressed. k1 is closed.
#define K1_PTS 64
__global__ __launch_bounds__(512) void k1_saliency(
    const float* __restrict__ x, const double* __restrict__ W1D,
    const double* __restrict__ b1D, const double* __restrict__ W2D,
    const double* __restrict__ b2D, double* __restrict__ salD,
    float* __restrict__ salF)
{
  __shared__ double smem[4008];              // 32064 B (xs + red overlay)
  float* xs = (float*)smem;                  // [64][125]
  int tid = threadIdx.x;
  int p0 = blockIdx.x * K1_PTS;

  { // stage x tile: 8000 floats = 2000 float4
    const float4* src = (const float4*)(x + (size_t)p0 * IN_DIM);
    float4* dst = (float4*)xs;
    for (int e = tid; e < (K1_PTS * IN_DIM) / 4; e += 512) dst[e] = src[e];
  }
  __syncthreads();

  int wv = __builtin_amdgcn_readfirstlane(tid >> 6);
  int lane = tid & 63;
  int jb = wv * 8;

  double acc[8];
  #pragma unroll
  for (int jj = 0; jj < 8; ++jj) acc[jj] = b1D[jb + jj];

  const float* xr = xs + lane * IN_DIM;      // stride 125 dwords: 2-way = free
  double wA[8], wB[8];
  #pragma unroll
  for (int jj = 0; jj < 8; ++jj) wA[jj] = W1D[jb + jj];    // row 0
  float xv0 = xr[0];

  #pragma unroll 1
  for (int d = 0; d < 124; d += 2) {
    float xv1 = xr[d + 1];
    #pragma unroll
    for (int jj = 0; jj < 8; ++jj) wB[jj] = W1D[(d + 1) * HID + jb + jj];
    double xd0 = (double)xv0;
    #pragma unroll
    for (int jj = 0; jj < 8; ++jj) acc[jj] = fma(xd0, wA[jj], acc[jj]);
    xv0 = xr[d + 2];
    #pragma unroll
    for (int jj = 0; jj < 8; ++jj) wA[jj] = W1D[(d + 2) * HID + jb + jj];
    double xd1 = (double)xv1;
    #pragma unroll
    for (int jj = 0; jj < 8; ++jj) acc[jj] = fma(xd1, wB[jj], acc[jj]);
  }
  { // d = 124 (wA holds row 124)
    double xd = (double)xv0;
    #pragma unroll
    for (int jj = 0; jj < 8; ++jj) acc[jj] = fma(xd, wA[jj], acc[jj]);
  }

  double part = 0.0;
  #pragma unroll
  for (int jj = 0; jj < 8; ++jj)
    part = fma(fmax(acc[jj], 0.0), W2D[jb + jj], part);
  __syncthreads();                           // xs reads done
  double* red = smem;                        // [8][64] overlay
  red[wv * K1_PTS + lane] = part;
  __syncthreads();
  if (tid < K1_PTS) {
    double s = b2D[0];
    #pragma unroll
    for (int w = 0; w < 8; ++w) s += red[w * K1_PTS + tid];
    double sg = 1.0 / (1.0 + exp(-s));
    salD[p0 + tid] = sg;                     // f64 sort key (monotone == y*)
    salF[p0 + tid] = (float)sg;
  }
}

// ---- kA: fused {k3a chunk-sort (blocks 0..255)} + {k2 softmax/cumsum
// (blocks 256..287)}. k3a now BARRIER-LIGHT: lanes remapped so wave w owns
// 128-elem span [128w,128w+128); bitonic pairs with j<=64 stay in-span ->
// same-wave DS ordering suffices (no __syncthreads). Only j>=128 rounds
// (3 of 45) need block barriers. Same network/comparator -> identical
// output to the r5-verified bitonic. ----
__global__ __launch_bounds__(256) void kA_softmax_sort(
    const double* __restrict__ salD, const float* __restrict__ salF,
    float* __restrict__ ystar, float* __restrict__ csal,
    unsigned long long* __restrict__ candK, int* __restrict__ candI)
{
  __shared__ unsigned long long K[512];
  __shared__ int I[512];
  __shared__ float wmax[4], wsum[4], wtot[4];
  int t = threadIdx.x;

  #define CSWAP(i, l, up) { \
    unsigned long long a = K[i], cc = K[l]; \
    int ai = I[i], ci = I[l]; \
    bool prec = (a > cc) || (a == cc && ai < ci); \
    if ((up) ? !prec : prec) { K[i] = cc; K[l] = a; I[i] = ci; I[l] = ai; } }

  if (blockIdx.x < 256) {
    // ---------------- k3a: sort 512-chunk desc, keep top-256 ------------
    int bid = blockIdx.x;
    int b = bid >> 3, c = bid & 7;
    const double* y = salD + (size_t)b * N_ + c * 512;
    for (int i = t; i < 512; i += 256) {
      K[i] = __double_as_longlong(y[i]);    // y in (0,1): bits monotone
      I[i] = c * 512 + i;
    }
    __syncthreads();

    int sw = ((t >> 6) << 7) + (t & 63);    // wave-span element 0 (own sw, sw+64)

    // levels k=2..128: every pair is within a 128-span -> wave-local
    for (int k = 2; k <= 128; k <<= 1) {
      for (int j = k >> 1; j > 0; j >>= 1) {
        #pragma unroll
        for (int h = 0; h < 2; ++h) {
          int i = sw + (h << 6);
          int l = i ^ j;
          if (l > i) CSWAP(i, l, ((i & k) == 0));
        }
      }
    }
    __syncthreads();

    { // level k=256: j=128 crosses spans (barrier), j<=64 wave-local
      for (int i = t; i < 512; i += 256) {
        int l = i ^ 128;
        if (l > i) CSWAP(i, l, ((i & 256) == 0));
      }
      __syncthreads();
      for (int j = 64; j > 0; j >>= 1) {
        #pragma unroll
        for (int h = 0; h < 2; ++h) {
          int i = sw + (h << 6);
          int l = i ^ j;
          if (l > i) CSWAP(i, l, ((i & 256) == 0));
        }
      }
    }
    __syncthreads();

    { // level k=512 (up==true everywhere): j=256,128 cross (barriers), rest local
      for (int i = t; i < 512; i += 256) {
        int l = i ^ 256;
        if (l > i) CSWAP(i, l, true);
      }
      __syncthreads();
      for (int i = t; i < 512; i += 256) {
        int l = i ^ 128;
        if (l > i) CSWAP(i, l, true);
      }
      __syncthreads();
      for (int j = 64; j > 0; j >>= 1) {
        #pragma unroll
        for (int h = 0; h < 2; ++h) {
          int i = sw + (h << 6);
          int l = i ^ j;
          if (l > i) CSWAP(i, l, true);
        }
      }
    }
    __syncthreads();

    if (t < 256) {
      candK[(b * 8 + c) * 256 + t] = K[t];
      candI[(b * 8 + c) * 256 + t] = I[t];
    }
  } else {
    // ---------------- k2: softmax(sal/0.5) + cumsum(sal)/N --------------
    int b = blockIdx.x - 256;
    int lane = t & 63, wv = t >> 6;
    const float4* s4 = (const float4*)(salF + (size_t)b * N_);
    float v[16];
    #pragma unroll
    for (int k = 0; k < 4; ++k) {
      float4 a = s4[t * 4 + k];
      v[4*k] = a.x; v[4*k+1] = a.y; v[4*k+2] = a.z; v[4*k+3] = a.w;
    }
    float m = v[0];
    #pragma unroll
    for (int i = 1; i < 16; ++i) m = fmaxf(m, v[i]);
    #pragma unroll
    for (int off = 32; off > 0; off >>= 1) m = fmaxf(m, __shfl_down(m, off));
    if (lane == 0) wmax[wv] = m;
    __syncthreads();
    float M = fmaxf(fmaxf(wmax[0], wmax[1]), fmaxf(wmax[2], wmax[3]));

    float e[16];
    float se = 0.f;
    #pragma unroll
    for (int i = 0; i < 16; ++i) { e[i] = expf((v[i] - M) * 2.0f); se += e[i]; }
    float ss = se;
    #pragma unroll
    for (int off = 32; off > 0; off >>= 1) ss += __shfl_down(ss, off);
    if (lane == 0) wsum[wv] = ss;
    __syncthreads();
    float denom = (wsum[0] + wsum[1]) + (wsum[2] + wsum[3]);
    float rdenom = 1.f / denom;

    float p[16];
    p[0] = v[0];
    #pragma unroll
    for (int i = 1; i < 16; ++i) p[i] = p[i-1] + v[i];
    float T = p[15];
    float incl = T;
    #pragma unroll
    for (int off = 1; off < 64; off <<= 1) {
      float nv = __shfl_up(incl, off);
      if (lane >= off) incl += nv;
    }
    float wexcl = incl - T;
    if (lane == 63) wtot[wv] = incl;
    __syncthreads();
    float woff = 0.f;
    for (int w = 0; w < 4; ++w) if (w < wv) woff += wtot[w];
    float base = woff + wexcl;

    float4* y4 = (float4*)(ystar + (size_t)b * N_);
    float4* c4 = (float4*)(csal + (size_t)b * N_);
    const float invN = 1.f / (float)N_;
    #pragma unroll
    for (int k = 0; k < 4; ++k) {
      float4 yo, co;
      yo.x = e[4*k]   * rdenom; co.x = (base + p[4*k])   * invN;
      yo.y = e[4*k+1] * rdenom; co.y = (base + p[4*k+1]) * invN;
      yo.z = e[4*k+2] * rdenom; co.z = (base + p[4*k+2]) * invN;
      yo.w = e[4*k+3] * rdenom; co.w = (base + p[4*k+3]) * invN;
      y4[t * 4 + k] = yo;
      c4[t * 4 + k] = co;
    }
  }
  #undef CSWAP
}

// ---- k4_fused: merge-path + gather/lift + proj. 1024 blocks (r6 lesson:
// preserve occupancy — 48KB pool -> 3 blocks/CU, and proj keeps its own
// block per col-group so its parallelism is NOT cut). Phase 1+2 bodies are
// r6-correctness-verified; phase 3 is k4b verbatim for one col-group.
// bid -> pg = bid>>2 (point-group 0..255), cg = bid&3 (col-group). The
// merge is redundant 4x per point-group (latency-parallel, ~3us). ----
__global__ __launch_bounds__(256) void k4_fused(
    const unsigned long long* __restrict__ candK, const int* __restrict__ candI,
    const float* __restrict__ x, const float* __restrict__ sal,
    const float* __restrict__ csal,
    const float* __restrict__ lift_W, const float* __restrict__ lift_b,
    const float* __restrict__ mu, const float* __restrict__ sigma,
    const float* __restrict__ proj_W, const float* __restrict__ proj_b,
    float* __restrict__ tokens)
{
  __shared__ __align__(16) char pool[49152];   // 48KB, phase-overlaid
  __shared__ int sidx[32];
  __shared__ float snf[32];
  int bid = blockIdx.x, t = threadIdx.x;
  int pg = bid >> 2, cg = bid & 3;
  int b = pg >> 3, p0 = (pg & 7) * 32;

  { // ---------- phase 1: merge-path top-256 of 8 sorted lists ----------
    unsigned long long* KA = (unsigned long long*)pool;            // [2048] 16K
    int* IA = (int*)(pool + 16384);                                // [2048]  8K
    unsigned long long* KB = (unsigned long long*)(pool + 24576);  // [1024]  8K
    int* IB = (int*)(pool + 32768);                                // [1024]  4K

    for (int i = t; i < 2048; i += 256) {
      KA[i] = candK[b * 2048 + i];
      IA[i] = candI[b * 2048 + i];
    }
    __syncthreads();

    // Level 1: 4 pairs of 256-lists in KA -> 4 top-256 lists in KB
    for (int e = t; e < 2048; e += 256) {
      int pr = e >> 9, q = e & 511;
      int own = q >> 8, pos = q & 255;
      int offSelf  = pr * 512 + own * 256;
      int offOther = pr * 512 + (own ^ 1) * 256;
      unsigned long long k = KA[offSelf + pos]; int idx = IA[offSelf + pos];
      int lo = 0, hi = 256;
      while (lo < hi) {
        int mid = (lo + hi) >> 1;
        unsigned long long ko = KA[offOther + mid]; int io = IA[offOther + mid];
        bool prec = (ko > k) || (ko == k && io < idx);
        if (prec) lo = mid + 1; else hi = mid;
      }
      int rank = pos + lo;
      if (rank < 256) { KB[pr * 256 + rank] = k; IB[pr * 256 + rank] = idx; }
    }
    __syncthreads();

    // Level 2: 2 pairs in KB -> 2 lists in KA[0..511]
    for (int e = t; e < 1024; e += 256) {
      int pr = e >> 9, q = e & 511;
      int own = q >> 8, pos = q & 255;
      int offSelf  = pr * 512 + own * 256;
      int offOther = pr * 512 + (own ^ 1) * 256;
      unsigned long long k = KB[offSelf + pos]; int idx = IB[offSelf + pos];
      int lo = 0, hi = 256;
      while (lo < hi) {
        int mid = (lo + hi) >> 1;
        unsigned long long ko = KB[offOther + mid]; int io = IB[offOther + mid];
        bool prec = (ko > k) || (ko == k && io < idx);
        if (prec) lo = mid + 1; else hi = mid;
      }
      int rank = pos + lo;
      if (rank < 256) { KA[pr * 256 + rank] = k; IA[pr * 256 + rank] = idx; }
    }
    __syncthreads();

    // Level 3: final pair; keep ranks in this block's slice [p0,p0+32)
    for (int e = t; e < 512; e += 256) {
      int own = e >> 8, pos = e & 255;
      int offSelf = own * 256, offOther = (own ^ 1) * 256;
      unsigned long long k = KA[offSelf + pos]; int idx = IA[offSelf + pos];
      int lo = 0, hi = 256;
      while (lo < hi) {
        int mid = (lo + hi) >> 1;
        unsigned long long ko = KA[offOther + mid]; int io = IA[offOther + mid];
        bool prec = (ko > k) || (ko == k && io < idx);
        if (prec) lo = mid + 1; else hi = mid;
      }
      int rank = pos + lo;
      if (rank >= p0 && rank < p0 + 32) sidx[rank - p0] = idx;
    }
    __syncthreads();           // sidx ready; KA/IA/KB/IB dead
  }

  // ---------- phase 2: gather -> normalize -> lift (verified body) ----
  float (*sd)[ADIM] = (float(*)[ADIM])pool;        // 16 KB (overlay)
  float* sW = (float*)(pool + 16384);              // 32 KB (overlay)

  for (int e = t; e < ADIM * KDIM; e += 256) sW[e] = lift_W[e];

  for (int e = t; e < 32 * ADIM; e += 256) {
    int p = e >> 7, a = e & 127;
    int n = sidx[p];
    int base = b * N_ + n;
    float v;
    if (a < IN_DIM)          v = x[(size_t)base * IN_DIM + a];
    else if (a == IN_DIM)    v = sal[base];
    else if (a == IN_DIM+1)  v = (float)n / (float)(N_ - 1);
    else                     v = csal[base];
    sd[p][a] = v;
  }
  __syncthreads();

  { // norms: 8 lanes per point
    int p = t >> 3, l8 = t & 7;
    float ss = 0.f;
    for (int a = l8; a < ADIM; a += 8) { float v = sd[p][a]; ss = fmaf(v, v, ss); }
    ss += __shfl_down(ss, 4);
    ss += __shfl_down(ss, 2);
    ss += __shfl_down(ss, 1);
    if (l8 == 0) snf[p] = 1.f / (sqrtf(ss) + EPS_);
  }
  __syncthreads();

  for (int e = t; e < 32 * ADIM; e += 256) {
    int p = e >> 7, a = e & 127;
    sd[p][a] = (sd[p][a] * snf[p] - mu[a]) / sigma[a];
  }
  __syncthreads();

  // lift: wave wv owns 8 points; lane = output dim k
  int wv = t >> 6, lane = t & 63;
  float lacc[8];
  {
    float lb = lift_b[lane];
    #pragma unroll
    for (int q = 0; q < 8; ++q) lacc[q] = lb;
    #pragma unroll 1
    for (int a = 0; a < ADIM; a += 4) {
      float wl0 = sW[a*KDIM+lane],     wl1 = sW[(a+1)*KDIM+lane];
      float wl2 = sW[(a+2)*KDIM+lane], wl3 = sW[(a+3)*KDIM+lane];
      #pragma unroll
      for (int q = 0; q < 8; ++q) {
        int p = wv * 8 + q;
        lacc[q] = fmaf(sd[p][a],   wl0, lacc[q]);
        lacc[q] = fmaf(sd[p][a+1], wl1, lacc[q]);
        lacc[q] = fmaf(sd[p][a+2], wl2, lacc[q]);
        lacc[q] = fmaf(sd[p][a+3], wl3, lacc[q]);
      }
    }
  }
  __syncthreads();                                 // all sd reads done
  float* sc = (float*)pool;                        // [32][64] 8 KB (overlays sd)
  #pragma unroll
  for (int q = 0; q < 8; ++q)
    sc[(wv * 8 + q) * KDIM + lane] = lacc[q];
  __syncthreads();

  // ---------- phase 3: proj, ONE col-group per block (k4b verbatim) ----
  int col = cg * 256 + t;
  float acc[32];
  #pragma unroll
  for (int p = 0; p < 32; ++p) acc[p] = 0.f;

  float4 wcur;
  wcur.x = proj_W[0*DMODEL + col]; wcur.y = proj_W[1*DMODEL + col];
  wcur.z = proj_W[2*DMODEL + col]; wcur.w = proj_W[3*DMODEL + col];
  #pragma unroll 1
  for (int c = 0; c < KDIM; c += 4) {
    float4 wnext = {0.f, 0.f, 0.f, 0.f};
    if (c + 4 < KDIM) {
      wnext.x = proj_W[(size_t)(c+4)*DMODEL + col];
      wnext.y = proj_W[(size_t)(c+5)*DMODEL + col];
      wnext.z = proj_W[(size_t)(c+6)*DMODEL + col];
      wnext.w = proj_W[(size_t)(c+7)*DMODEL + col];
    }
    #pragma unroll
    for (int p = 0; p < 32; ++p) {
      float4 cv = *(const float4*)&sc[p * KDIM + c];   // broadcast b128
      acc[p] = fmaf(cv.x, wcur.x, acc[p]);
      acc[p] = fmaf(cv.y, wcur.y, acc[p]);
      acc[p] = fmaf(cv.z, wcur.z, acc[p]);
      acc[p] = fmaf(cv.w, wcur.w, acc[p]);
    }
    wcur = wnext;
  }

  float pb = proj_b[col];
  int gp0 = pg * 32;
  #pragma unroll
  for (int p = 0; p < 32; ++p)
    tokens[(size_t)(gp0 + p) * DMODEL + col] = acc[p] + pb;
}

extern "C" void kernel_launch(void* const* d_in, const int* in_sizes, int n_in,
                              void* d_out, int out_size, void* d_ws, size_t ws_size,
                              hipStream_t stream)
{
  const float* x      = (const float*)d_in[0];
  const float* W1     = (const float*)d_in[1];
  const float* b1     = (const float*)d_in[2];
  const float* W2     = (const float*)d_in[3];
  const float* b2     = (const float*)d_in[4];
  const float* lift_W = (const float*)d_in[5];
  const float* lift_b = (const float*)d_in[6];
  const float* mu     = (const float*)d_in[7];
  const float* sigma  = (const float*)d_in[8];
  const float* proj_W = (const float*)d_in[9];
  const float* proj_b = (const float*)d_in[10];

  float* tokens = (float*)d_out;                        // [B,256,1024]
  float* ystarF = tokens + (size_t)B_ * KEFF * DMODEL;  // [B,N]

  // workspace layout (no overlays needed):
  //   [0,1MB): salD | [1,1.5MB): candK | [1.5,1.75MB): candI
  //   [1.75MB,+65K): W1D/b1D/W2D/b2D | [2,2.5MB): salF | [2.5,3MB): csalF
  char* wsb = (char*)d_ws;
  double* salD   = (double*)wsb;                                   // B*N f64
  unsigned long long* candK = (unsigned long long*)(wsb + (1<<20));
  int*    candI  = (int*)(wsb + (1<<20) + (512<<10));
  double* W1D    = (double*)(wsb + (1<<20) + (768<<10));
  double* b1D    = W1D + IN_DIM * HID;
  double* W2D    = b1D + HID;
  double* b2D    = W2D + HID;
  float*  salF   = (float*)(wsb + (2<<20));
  float*  csalF  = salF + (size_t)B_ * N_;

  k0_cvt<<<(IN_DIM * HID + 255) / 256, 256, 0, stream>>>(
      W1, b1, W2, b2, W1D, b1D, W2D, b2D);
  k1_saliency<<<(B_ * N_) / K1_PTS, 512, 0, stream>>>(
      x, W1D, b1D, W2D, b2D, salD, salF);
  kA_softmax_sort<<<256 + B_, 256, 0, stream>>>(
      salD, salF, ystarF, csalF, candK, candI);
  k4_fused<<<B_ * KEFF / 32 * 4, 256, 0, stream>>>(
      candK, candI, x, salF, csalF, lift_W, lift_b, mu, sigma,
      proj_W, proj_b, tokens);
}

// Round 9
// 236.972 us; speedup vs baseline: 1.1543x; 1.1543x over previous
//
#include <hip/hip_runtime.h>
#include <cmath>

#define B_ 32
#define N_ 4096
#define IN_DIM 125
#define ADIM 128
#define KDIM 64
#define DMODEL 1024
#define HID 64
#define KEFF 256
#define EPS_ 1e-6f

// ---------- k0: convert MLP weights to f64 (once per launch) ----------
// Kept separate: r5 proved inlining the f32->f64 cvt into k1's loop costs
// +16us of f64-pipe time vs ~12us for this launch+run.
__global__ __launch_bounds__(256) void k0_cvt(
    const float* __restrict__ W1, const float* __restrict__ b1,
    const float* __restrict__ W2, const float* __restrict__ b2,
    double* __restrict__ W1D, double* __restrict__ b1D,
    double* __restrict__ W2D, double* __restrict__ b2D)
{
  int t = blockIdx.x * 256 + threadIdx.x;
  if (t < IN_DIM * HID) W1D[t] = (double)W1[t];
  if (t < HID) { b1D[t] = (double)b1[t]; W2D[t] = (double)W2[t]; }
  if (t == 0) b2D[0] = (double)b2[0];
}

// ---------- k1: saliency MLP in fp64 (r0 version — all-time best) ----------
// r0-r8 verdict: 64 pts/block, s_load f64-W, 1 pt/lane = 58-64us at
// VALU ~52-58%, occ ~70%. Every restructure regressed. k1 is closed.
#define K1_PTS 64
__global__ __launch_bounds__(512) void k1_saliency(
    const float* __restrict__ x, const double* __restrict__ W1D,
    const double* __restrict__ b1D, const double* __restrict__ W2D,
    const double* __restrict__ b2D, double* __restrict__ salD,
    float* __restrict__ salF)
{
  __shared__ double smem[4008];              // 32064 B (xs + red overlay)
  float* xs = (float*)smem;                  // [64][125]
  int tid = threadIdx.x;
  int p0 = blockIdx.x * K1_PTS;

  { // stage x tile: 8000 floats = 2000 float4
    const float4* src = (const float4*)(x + (size_t)p0 * IN_DIM);
    float4* dst = (float4*)xs;
    for (int e = tid; e < (K1_PTS * IN_DIM) / 4; e += 512) dst[e] = src[e];
  }
  __syncthreads();

  int wv = __builtin_amdgcn_readfirstlane(tid >> 6);
  int lane = tid & 63;
  int jb = wv * 8;

  double acc[8];
  #pragma unroll
  for (int jj = 0; jj < 8; ++jj) acc[jj] = b1D[jb + jj];

  const float* xr = xs + lane * IN_DIM;      // stride 125 dwords: 2-way = free
  double wA[8], wB[8];
  #pragma unroll
  for (int jj = 0; jj < 8; ++jj) wA[jj] = W1D[jb + jj];    // row 0
  float xv0 = xr[0];

  #pragma unroll 1
  for (int d = 0; d < 124; d += 2) {
    float xv1 = xr[d + 1];
    #pragma unroll
    for (int jj = 0; jj < 8; ++jj) wB[jj] = W1D[(d + 1) * HID + jb + jj];
    double xd0 = (double)xv0;
    #pragma unroll
    for (int jj = 0; jj < 8; ++jj) acc[jj] = fma(xd0, wA[jj], acc[jj]);
    xv0 = xr[d + 2];
    #pragma unroll
    for (int jj = 0; jj < 8; ++jj) wA[jj] = W1D[(d + 2) * HID + jb + jj];
    double xd1 = (double)xv1;
    #pragma unroll
    for (int jj = 0; jj < 8; ++jj) acc[jj] = fma(xd1, wB[jj], acc[jj]);
  }
  { // d = 124 (wA holds row 124)
    double xd = (double)xv0;
    #pragma unroll
    for (int jj = 0; jj < 8; ++jj) acc[jj] = fma(xd, wA[jj], acc[jj]);
  }

  double part = 0.0;
  #pragma unroll
  for (int jj = 0; jj < 8; ++jj)
    part = fma(fmax(acc[jj], 0.0), W2D[jb + jj], part);
  __syncthreads();                           // xs reads done
  double* red = smem;                        // [8][64] overlay
  red[wv * K1_PTS + lane] = part;
  __syncthreads();
  if (tid < K1_PTS) {
    double s = b2D[0];
    #pragma unroll
    for (int w = 0; w < 8; ++w) s += red[w * K1_PTS + tid];
    double sg = 1.0 / (1.0 + exp(-s));
    salD[p0 + tid] = sg;                     // f64 sort key (monotone == y*)
    salF[p0 + tid] = (float)sg;
  }
}

// ---- kA: fused {k3a chunk-sort (blocks 0..255)} + {k2 softmax/cumsum
// (blocks 256..287)}. k3a BARRIER-LIGHT (r8-verified correct): wave w owns
// 128-elem span; bitonic pairs with j<=64 stay in-span -> wave-local DS
// ordering, no __syncthreads. Only j>=128 rounds need block barriers. ----
__global__ __launch_bounds__(256) void kA_softmax_sort(
    const double* __restrict__ salD, const float* __restrict__ salF,
    float* __restrict__ ystar, float* __restrict__ csal,
    unsigned long long* __restrict__ candK, int* __restrict__ candI)
{
  __shared__ unsigned long long K[512];
  __shared__ int I[512];
  __shared__ float wmax[4], wsum[4], wtot[4];
  int t = threadIdx.x;

  #define CSWAP(i, l, up) { \
    unsigned long long a = K[i], cc = K[l]; \
    int ai = I[i], ci = I[l]; \
    bool prec = (a > cc) || (a == cc && ai < ci); \
    if ((up) ? !prec : prec) { K[i] = cc; K[l] = a; I[i] = ci; I[l] = ai; } }

  if (blockIdx.x < 256) {
    // ---------------- k3a: sort 512-chunk desc, keep top-256 ------------
    int bid = blockIdx.x;
    int b = bid >> 3, c = bid & 7;
    const double* y = salD + (size_t)b * N_ + c * 512;
    for (int i = t; i < 512; i += 256) {
      K[i] = __double_as_longlong(y[i]);    // y in (0,1): bits monotone
      I[i] = c * 512 + i;
    }
    __syncthreads();

    int sw = ((t >> 6) << 7) + (t & 63);    // wave-span element 0

    // levels k=2..128: every pair is within a 128-span -> wave-local
    for (int k = 2; k <= 128; k <<= 1) {
      for (int j = k >> 1; j > 0; j >>= 1) {
        #pragma unroll
        for (int h = 0; h < 2; ++h) {
          int i = sw + (h << 6);
          int l = i ^ j;
          if (l > i) CSWAP(i, l, ((i & k) == 0));
        }
      }
    }
    __syncthreads();

    { // level k=256: j=128 crosses spans (barrier), j<=64 wave-local
      for (int i = t; i < 512; i += 256) {
        int l = i ^ 128;
        if (l > i) CSWAP(i, l, ((i & 256) == 0));
      }
      __syncthreads();
      for (int j = 64; j > 0; j >>= 1) {
        #pragma unroll
        for (int h = 0; h < 2; ++h) {
          int i = sw + (h << 6);
          int l = i ^ j;
          if (l > i) CSWAP(i, l, ((i & 256) == 0));
        }
      }
    }
    __syncthreads();

    { // level k=512 (up everywhere): j=256,128 cross (barriers), rest local
      for (int i = t; i < 512; i += 256) {
        int l = i ^ 256;
        if (l > i) CSWAP(i, l, true);
      }
      __syncthreads();
      for (int i = t; i < 512; i += 256) {
        int l = i ^ 128;
        if (l > i) CSWAP(i, l, true);
      }
      __syncthreads();
      for (int j = 64; j > 0; j >>= 1) {
        #pragma unroll
        for (int h = 0; h < 2; ++h) {
          int i = sw + (h << 6);
          int l = i ^ j;
          if (l > i) CSWAP(i, l, true);
        }
      }
    }
    __syncthreads();

    if (t < 256) {
      candK[(b * 8 + c) * 256 + t] = K[t];
      candI[(b * 8 + c) * 256 + t] = I[t];
    }
  } else {
    // ---------------- k2: softmax(sal/0.5) + cumsum(sal)/N --------------
    int b = blockIdx.x - 256;
    int lane = t & 63, wv = t >> 6;
    const float4* s4 = (const float4*)(salF + (size_t)b * N_);
    float v[16];
    #pragma unroll
    for (int k = 0; k < 4; ++k) {
      float4 a = s4[t * 4 + k];
      v[4*k] = a.x; v[4*k+1] = a.y; v[4*k+2] = a.z; v[4*k+3] = a.w;
    }
    float m = v[0];
    #pragma unroll
    for (int i = 1; i < 16; ++i) m = fmaxf(m, v[i]);
    #pragma unroll
    for (int off = 32; off > 0; off >>= 1) m = fmaxf(m, __shfl_down(m, off));
    if (lane == 0) wmax[wv] = m;
    __syncthreads();
    float M = fmaxf(fmaxf(wmax[0], wmax[1]), fmaxf(wmax[2], wmax[3]));

    float e[16];
    float se = 0.f;
    #pragma unroll
    for (int i = 0; i < 16; ++i) { e[i] = expf((v[i] - M) * 2.0f); se += e[i]; }
    float ss = se;
    #pragma unroll
    for (int off = 32; off > 0; off >>= 1) ss += __shfl_down(ss, off);
    if (lane == 0) wsum[wv] = ss;
    __syncthreads();
    float denom = (wsum[0] + wsum[1]) + (wsum[2] + wsum[3]);
    float rdenom = 1.f / denom;

    float p[16];
    p[0] = v[0];
    #pragma unroll
    for (int i = 1; i < 16; ++i) p[i] = p[i-1] + v[i];
    float T = p[15];
    float incl = T;
    #pragma unroll
    for (int off = 1; off < 64; off <<= 1) {
      float nv = __shfl_up(incl, off);
      if (lane >= off) incl += nv;
    }
    float wexcl = incl - T;
    if (lane == 63) wtot[wv] = incl;
    __syncthreads();
    float woff = 0.f;
    for (int w = 0; w < 4; ++w) if (w < wv) woff += wtot[w];
    float base = woff + wexcl;

    float4* y4 = (float4*)(ystar + (size_t)b * N_);
    float4* c4 = (float4*)(csal + (size_t)b * N_);
    const float invN = 1.f / (float)N_;
    #pragma unroll
    for (int k = 0; k < 4; ++k) {
      float4 yo, co;
      yo.x = e[4*k]   * rdenom; co.x = (base + p[4*k])   * invN;
      yo.y = e[4*k+1] * rdenom; co.y = (base + p[4*k+1]) * invN;
      yo.z = e[4*k+2] * rdenom; co.z = (base + p[4*k+2]) * invN;
      yo.w = e[4*k+3] * rdenom; co.w = (base + p[4*k+3]) * invN;
      y4[t * 4 + k] = yo;
      c4[t * 4 + k] = co;
    }
  }
  #undef CSWAP
}

// ---- k3b: merge-path top-256 of 8 sorted lists (r5/r7-validated). ----
__global__ __launch_bounds__(256) void k3b_merge(
    const unsigned long long* __restrict__ candK, const int* __restrict__ candI,
    int* __restrict__ topidx)
{
  __shared__ unsigned long long KA[2048];   // 16 KB
  __shared__ int IA[2048];                  //  8 KB
  __shared__ unsigned long long KB[1024];   //  8 KB
  __shared__ int IB[1024];                  //  4 KB
  int b = blockIdx.x, t = threadIdx.x;

  for (int i = t; i < 2048; i += 256) {
    KA[i] = candK[b * 2048 + i];
    IA[i] = candI[b * 2048 + i];
  }
  __syncthreads();

  // Level 1: 4 pairs of 256-lists in KA -> 4 top-256 lists in KB
  for (int e = t; e < 2048; e += 256) {
    int pr = e >> 9, q = e & 511;
    int own = q >> 8, pos = q & 255;
    int offSelf  = pr * 512 + own * 256;
    int offOther = pr * 512 + (own ^ 1) * 256;
    unsigned long long k = KA[offSelf + pos]; int idx = IA[offSelf + pos];
    int lo = 0, hi = 256;
    while (lo < hi) {
      int mid = (lo + hi) >> 1;
      unsigned long long ko = KA[offOther + mid]; int io = IA[offOther + mid];
      bool prec = (ko > k) || (ko == k && io < idx);
      if (prec) lo = mid + 1; else hi = mid;
    }
    int rank = pos + lo;
    if (rank < 256) { KB[pr * 256 + rank] = k; IB[pr * 256 + rank] = idx; }
  }
  __syncthreads();

  // Level 2: 2 pairs in KB -> 2 lists in KA[0..511]
  for (int e = t; e < 1024; e += 256) {
    int pr = e >> 9, q = e & 511;
    int own = q >> 8, pos = q & 255;
    int offSelf  = pr * 512 + own * 256;
    int offOther = pr * 512 + (own ^ 1) * 256;
    unsigned long long k = KB[offSelf + pos]; int idx = IB[offSelf + pos];
    int lo = 0, hi = 256;
    while (lo < hi) {
      int mid = (lo + hi) >> 1;
      unsigned long long ko = KB[offOther + mid]; int io = IB[offOther + mid];
      bool prec = (ko > k) || (ko == k && io < idx);
      if (prec) lo = mid + 1; else hi = mid;
    }
    int rank = pos + lo;
    if (rank < 256) { KA[pr * 256 + rank] = k; IA[pr * 256 + rank] = idx; }
  }
  __syncthreads();

  // Level 3: final pair KA[0..255] x KA[256..511] -> topidx (global)
  for (int e = t; e < 512; e += 256) {
    int own = e >> 8, pos = e & 255;
    int offSelf = own * 256, offOther = (own ^ 1) * 256;
    unsigned long long k = KA[offSelf + pos]; int idx = IA[offSelf + pos];
    int lo = 0, hi = 256;
    while (lo < hi) {
      int mid = (lo + hi) >> 1;
      unsigned long long ko = KA[offOther + mid]; int io = IA[offOther + mid];
      bool prec = (ko > k) || (ko == k && io < idx);
      if (prec) lo = mid + 1; else hi = mid;
    }
    int rank = pos + lo;
    if (rank < 256) topidx[b * KEFF + rank] = idx;
  }
}

// ---- k4a: gather top-32/block, dense->normalize->lift -> cloud[8192][64] ----
__global__ __launch_bounds__(256) void k4a_lift(
    const float* __restrict__ x, const float* __restrict__ sal,
    const float* __restrict__ csal, const int* __restrict__ topidx,
    const float* __restrict__ lift_W, const float* __restrict__ lift_b,
    const float* __restrict__ mu, const float* __restrict__ sigma,
    float* __restrict__ cloud)
{
  __shared__ float sd[32][ADIM];      // 16KB
  __shared__ float sW[ADIM * KDIM];   // 32KB
  __shared__ float snf[32];
  __shared__ int sidx[32];

  int t = threadIdx.x, bid = blockIdx.x;
  int b = bid >> 3, p0 = (bid & 7) * 32;

  if (t < 32) sidx[t] = topidx[b * KEFF + p0 + t];
  for (int e = t; e < ADIM * KDIM; e += 256) sW[e] = lift_W[e];
  __syncthreads();

  for (int e = t; e < 32 * ADIM; e += 256) {
    int p = e >> 7, a = e & 127;
    int n = sidx[p];
    int base = b * N_ + n;
    float v;
    if (a < IN_DIM)          v = x[(size_t)base * IN_DIM + a];
    else if (a == IN_DIM)    v = sal[base];
    else if (a == IN_DIM+1)  v = (float)n / (float)(N_ - 1);
    else                     v = csal[base];
    sd[p][a] = v;
  }
  __syncthreads();

  { // norms: 8 lanes per point
    int p = t >> 3, l8 = t & 7;
    float ss = 0.f;
    for (int a = l8; a < ADIM; a += 8) { float v = sd[p][a]; ss = fmaf(v, v, ss); }
    ss += __shfl_down(ss, 4);
    ss += __shfl_down(ss, 2);
    ss += __shfl_down(ss, 1);
    if (l8 == 0) snf[p] = 1.f / (sqrtf(ss) + EPS_);
  }
  __syncthreads();

  for (int e = t; e < 32 * ADIM; e += 256) {
    int p = e >> 7, a = e & 127;
    sd[p][a] = (sd[p][a] * snf[p] - mu[a]) / sigma[a];
  }
  __syncthreads();

  // lift: wave wv owns 8 points; lane = output dim k
  int wv = t >> 6, lane = t & 63;
  float acc[8];
  float lb = lift_b[lane];
  #pragma unroll
  for (int q = 0; q < 8; ++q) acc[q] = lb;
  #pragma unroll 1
  for (int a = 0; a < ADIM; a += 4) {
    float wl0 = sW[a*KDIM+lane],     wl1 = sW[(a+1)*KDIM+lane];
    float wl2 = sW[(a+2)*KDIM+lane], wl3 = sW[(a+3)*KDIM+lane];
    #pragma unroll
    for (int q = 0; q < 8; ++q) {
      int p = wv * 8 + q;
      acc[q] = fmaf(sd[p][a],   wl0, acc[q]);
      acc[q] = fmaf(sd[p][a+1], wl1, acc[q]);
      acc[q] = fmaf(sd[p][a+2], wl2, acc[q]);
      acc[q] = fmaf(sd[p][a+3], wl3, acc[q]);
    }
  }
  #pragma unroll
  for (int q = 0; q < 8; ++q) {
    int gp = b * KEFF + p0 + wv * 8 + q;
    cloud[(size_t)gp * KDIM + lane] = acc[q];    // coalesced 64 dwords
  }
}

// ---- k4b: proj GEMM. Block = 32 points x 256 cols; 1024 blocks. ----
__global__ __launch_bounds__(256) void k4b_proj(
    const float* __restrict__ cloud, const float* __restrict__ proj_W,
    const float* __restrict__ proj_b, float* __restrict__ tokens)
{
  __shared__ float sc[32][KDIM];      // 8KB
  int t = threadIdx.x;
  int pg = blockIdx.x >> 2, cg = blockIdx.x & 3;

  { // load cloud tile: 2048 floats = 512 float4
    const float4* src = (const float4*)(cloud + (size_t)pg * 32 * KDIM);
    float4* dst = (float4*)sc;
    dst[t] = src[t];
    dst[t + 256] = src[t + 256];
  }
  __syncthreads();

  int col = cg * 256 + t;
  float acc[32];
  #pragma unroll
  for (int p = 0; p < 32; ++p) acc[p] = 0.f;

  float4 wcur;
  wcur.x = proj_W[0*DMODEL + col]; wcur.y = proj_W[1*DMODEL + col];
  wcur.z = proj_W[2*DMODEL + col]; wcur.w = proj_W[3*DMODEL + col];
  #pragma unroll 1
  for (int c = 0; c < KDIM; c += 4) {
    float4 wnext = {0.f, 0.f, 0.f, 0.f};
    if (c + 4 < KDIM) {
      wnext.x = proj_W[(size_t)(c+4)*DMODEL + col];
      wnext.y = proj_W[(size_t)(c+5)*DMODEL + col];
      wnext.z = proj_W[(size_t)(c+6)*DMODEL + col];
      wnext.w = proj_W[(size_t)(c+7)*DMODEL + col];
    }
    #pragma unroll
    for (int p = 0; p < 32; ++p) {
      float4 cv = *(const float4*)&sc[p][c];     // broadcast b128
      acc[p] = fmaf(cv.x, wcur.x, acc[p]);
      acc[p] = fmaf(cv.y, wcur.y, acc[p]);
      acc[p] = fmaf(cv.z, wcur.z, acc[p]);
      acc[p] = fmaf(cv.w, wcur.w, acc[p]);
    }
    wcur = wnext;
  }

  float pb = proj_b[col];
  int gp0 = pg * 32;
  #pragma unroll
  for (int p = 0; p < 32; ++p)
    tokens[(size_t)(gp0 + p) * DMODEL + col] = acc[p] + pb;
}

extern "C" void kernel_launch(void* const* d_in, const int* in_sizes, int n_in,
                              void* d_out, int out_size, void* d_ws, size_t ws_size,
                              hipStream_t stream)
{
  const float* x      = (const float*)d_in[0];
  const float* W1     = (const float*)d_in[1];
  const float* b1     = (const float*)d_in[2];
  const float* W2     = (const float*)d_in[3];
  const float* b2     = (const float*)d_in[4];
  const float* lift_W = (const float*)d_in[5];
  const float* lift_b = (const float*)d_in[6];
  const float* mu     = (const float*)d_in[7];
  const float* sigma  = (const float*)d_in[8];
  const float* proj_W = (const float*)d_in[9];
  const float* proj_b = (const float*)d_in[10];

  float* tokens = (float*)d_out;                        // [B,256,1024]
  float* ystarF = tokens + (size_t)B_ * KEFF * DMODEL;  // [B,N]

  // workspace layout with overlay (r0/r7-proven):
  //   [0, 2MB): salD(1MB) | candK(512K) | candI(256K)  -- all dead after k3b
  //             cloud(2MB) overlays this region (written by k4a)
  //   [2MB,..): W1D/b1D/W2D/b2D (~65KB) | salF(512K) | csalF(512K) | topidx(32K)
  char* wsb = (char*)d_ws;
  double* salD   = (double*)wsb;                                   // B*N f64
  unsigned long long* candK = (unsigned long long*)(wsb + (1<<20));
  int*    candI  = (int*)(wsb + (1<<20) + (512<<10));
  float*  cloud  = (float*)wsb;                                    // overlay
  double* W1D    = (double*)(wsb + (2<<20));
  double* b1D    = W1D + IN_DIM * HID;
  double* W2D    = b1D + HID;
  double* b2D    = W2D + HID;
  float*  salF   = (float*)(wsb + (2<<20) + 65536);
  float*  csalF  = salF + (size_t)B_ * N_;
  int*    topidx = (int*)(csalF + (size_t)B_ * N_);

  k0_cvt<<<(IN_DIM * HID + 255) / 256, 256, 0, stream>>>(
      W1, b1, W2, b2, W1D, b1D, W2D, b2D);
  k1_saliency<<<(B_ * N_) / K1_PTS, 512, 0, stream>>>(
      x, W1D, b1D, W2D, b2D, salD, salF);
  kA_softmax_sort<<<256 + B_, 256, 0, stream>>>(
      salD, salF, ystarF, csalF, candK, candI);
  k3b_merge<<<B_, 256, 0, stream>>>(candK, candI, topidx);
  k4a_lift<<<B_ * 8, 256, 0, stream>>>(
      x, salF, csalF, topidx, lift_W, lift_b, mu, sigma, cloud);
  k4b_proj<<<(B_ * KEFF / 32) * (DMODEL / 256), 256, 0, stream>>>(
      cloud, proj_W, proj_b, tokens);
}